// Round 8
// baseline (1988.715 us; speedup 1.0000x reference)
//
#include <hip/hip_runtime.h>

typedef __bf16 bf16x8 __attribute__((ext_vector_type(8)));
typedef float  f32x4  __attribute__((ext_vector_type(4)));

constexpr int Bb = 8, Ss = 1024, Ee = 768, Hh = 12, Ll = 6, Ff = 3072;
constexpr int TOK  = Bb * Ss;      // 8192
constexpr int NQKV = 3 * Ee;       // 2304

static __device__ __forceinline__ f32x4 mfma16(bf16x8 a, bf16x8 b, f32x4 c) {
  return __builtin_amdgcn_mfma_f32_16x16x32_bf16(a, b, c, 0, 0, 0);
}

// async global->LDS, 16B per lane. LDS dest is wave-uniform base + lane*16.
static __device__ __forceinline__ void async16(const void* g, void* l) {
  __builtin_amdgcn_global_load_lds(
      (const __attribute__((address_space(1))) unsigned int*)g,
      (__attribute__((address_space(3))) unsigned int*)l, 16, 0, 0);
}

// inline-asm ds_read_b128: invisible to the compiler's vmcnt alias tracking,
// so it cannot conservatively insert s_waitcnt vmcnt(0) before it (which
// would defeat the counted-vmcnt ring pipeline). MUST be followed by
// lgkmcnt(0) + sched_barrier(0) before any consumer (rule 18).
static __device__ __forceinline__ bf16x8 ds_read128(const __bf16* p) {
  bf16x8 r;
  unsigned a = (unsigned)(size_t)p;      // LDS pointers are 32-bit offsets
  asm volatile("ds_read_b128 %0, %1" : "=v"(r) : "v"(a));
  return r;
}

// raw v_exp_f32 (computes 2^x); HW-interlocked on CDNA.
static __device__ __forceinline__ float fexp2(float x) {
  float r; asm("v_exp_f32 %0, %1" : "=v"(r) : "v"(x)); return r;
}

// ---------------- embedding + positional encoding ----------------
__global__ __launch_bounds__(256) void embed_kernel(
    const int* __restrict__ ids, const float* __restrict__ emb,
    const float* __restrict__ pe, float* __restrict__ x, __bf16* __restrict__ xb)
{
  int tok = blockIdx.x;
  int s   = tok & (Ss - 1);
  int id  = ids[tok];
  const float* er = emb + (size_t)id * Ee;
  const float* pr = pe  + (size_t)s  * Ee;
  size_t base = (size_t)tok * Ee;
#pragma unroll
  for (int i = 0; i < 3; i++) {
    int e = threadIdx.x + i * 256;
    float v = er[e] + pr[e];
    x[base + e]  = v;
    xb[base + e] = (__bf16)v;
  }
}

// ---------------- weight transpose fp32 (K x N) -> bf16 (N x K) ----------------
__global__ __launch_bounds__(256) void transpose_w_kernel(
    const float* __restrict__ src, __bf16* __restrict__ dst,
    int K, int N, size_t sls, size_t dls)
{
  __shared__ float t[32][33];
  src += (size_t)blockIdx.z * sls;
  dst += (size_t)blockIdx.z * dls;
  int n0 = blockIdx.x * 32, k0 = blockIdx.y * 32;
  int c = threadIdx.x & 31, r0 = threadIdx.x >> 5;
#pragma unroll
  for (int rr = 0; rr < 32; rr += 8)
    t[r0 + rr][c] = src[(size_t)(k0 + r0 + rr) * N + n0 + c];
  __syncthreads();
#pragma unroll
  for (int rr = 0; rr < 32; rr += 8)
    dst[(size_t)(n0 + r0 + rr) * K + k0 + c] = (__bf16)t[c][r0 + rr];
}

// ---------------- small GEMM (R6-verified): 128x128 block, waves 64x64 ------
// Ring-3 LDS + counted vmcnt + asm ds_read. Used for QKV and FFN1
// (large-N GEMMs where grid 64*(N/128) >= 2.25 blocks/CU).
template<bool OUT_BF16, bool RELU>
__global__ __launch_bounds__(256, 3) void gemm_kernel(
    const __bf16* __restrict__ A, const __bf16* __restrict__ Bt,
    const float* __restrict__ bias0, const float* __restrict__ bias1,
    const float* __restrict__ bias2, int bseg,
    float* __restrict__ Cf, __bf16* __restrict__ Cb, int M, int N, int K)
{
  __shared__ __align__(16) __bf16 lA[3][64 * 64];
  __shared__ __align__(16) __bf16 lB[3][64 * 64];
  const int tid  = threadIdx.x;
  const int wave = tid >> 6, lane = tid & 63;
  const int quad = lane >> 4, c16 = lane & 15;
  const int wm = wave >> 1, wn = wave & 1;

  const int bid = blockIdx.x;
  const int xcd = bid & 7;
  const int lb  = bid >> 3;
  const int mb  = xcd * 8 + (lb & 7);   // M/128 == 64 always
  const int nb  = lb >> 3;
  const size_t m0 = (size_t)mb * 128, n0 = (size_t)nb * 128;

  f32x4 acc[4][4] = {};

  const int s0l = tid >> 3;
  const int s0c = tid & 7;
  const int l0  = s0c ^ (s0l & 7);
  const int tr0 = (s0l << 1) | (l0 >> 2);
  const int gc0 = (l0 & 3) * 8;
  const int s1l = (tid + 256) >> 3;
  const int l1  = s0c ^ (s1l & 7);
  const int tr1 = (s1l << 1) | (l1 >> 2);
  const int gc1 = (l1 & 3) * 8;

  const __bf16* Ag0 = A  + (m0 + tr0) * K + gc0;
  const __bf16* Ag1 = A  + (m0 + tr1) * K + gc1;
  const __bf16* Bg0 = Bt + (n0 + tr0) * K + gc0;
  const __bf16* Bg1 = Bt + (n0 + tr1) * K + gc1;
  const int d0 = tid * 8;

  const int nk = K >> 5;

  auto stage = [&](int t, int slot) {
    const int kof = t << 5;
    async16(Ag0 + kof, &lA[slot][d0]);
    async16(Ag1 + kof, &lA[slot][d0 + 2048]);
    async16(Bg0 + kof, &lB[slot][d0]);
    async16(Bg1 + kof, &lB[slot][d0 + 2048]);
  };

  int aoff[4], boff[4];
#pragma unroll
  for (int f = 0; f < 4; f++) {
    int ra = wm * 64 + f * 16 + c16;
    int ja = ra >> 1;
    aoff[f] = ja * 64 + (((((ra & 1) << 2) | quad)) ^ (ja & 7)) * 8;
    int rb = wn * 64 + f * 16 + c16;
    int jb = rb >> 1;
    boff[f] = jb * 64 + (((((rb & 1) << 2) | quad)) ^ (jb & 7)) * 8;
  }

  stage(0, 0);
  stage(1, 1);
  asm volatile("s_waitcnt vmcnt(4)" ::: "memory");
  __builtin_amdgcn_s_barrier();
  __builtin_amdgcn_sched_barrier(0);

  int slot = 0;
  for (int t = 0; t < nk; ++t) {
    if (t + 2 < nk) {
      int ns = slot + 2; if (ns >= 3) ns -= 3;
      stage(t + 2, ns);
    }
    const __bf16* la = &lA[slot][0];
    const __bf16* lb = &lB[slot][0];
    bf16x8 af[4], bfr[4];
#pragma unroll
    for (int f = 0; f < 4; f++) af[f]  = ds_read128(la + aoff[f]);
#pragma unroll
    for (int f = 0; f < 4; f++) bfr[f] = ds_read128(lb + boff[f]);
    asm volatile("s_waitcnt lgkmcnt(0)" ::: "memory");
    __builtin_amdgcn_sched_barrier(0);
    __builtin_amdgcn_s_setprio(1);
#pragma unroll
    for (int mi = 0; mi < 4; mi++)
#pragma unroll
      for (int ni = 0; ni < 4; ni++)
        acc[mi][ni] = mfma16(af[mi], bfr[ni], acc[mi][ni]);
    __builtin_amdgcn_s_setprio(0);
    __builtin_amdgcn_sched_barrier(0);
    if (t + 2 < nk) asm volatile("s_waitcnt vmcnt(4)" ::: "memory");
    else            asm volatile("s_waitcnt vmcnt(0)" ::: "memory");
    __builtin_amdgcn_s_barrier();
    __builtin_amdgcn_sched_barrier(0);
    slot = (slot + 1 == 3) ? 0 : slot + 1;
  }

#pragma unroll
  for (int ni = 0; ni < 4; ni++) {
    int col = (int)n0 + wn * 64 + ni * 16 + c16;
    const float* bp = bias0;
    int cc = col;
    if (cc >= bseg) { bp = bias1; cc -= bseg; }
    if (cc >= bseg) { bp = bias2; cc -= bseg; }
    float bv = bp[cc];
#pragma unroll
    for (int mi = 0; mi < 4; mi++) {
#pragma unroll
      for (int rr = 0; rr < 4; rr++) {
        size_t row = m0 + wm * 64 + mi * 16 + quad * 4 + rr;
        float v = acc[mi][ni][rr] + bv;
        if (RELU) v = fmaxf(v, 0.f);
        if (OUT_BF16) Cb[row * N + col] = (__bf16)v;
        else          Cf[row * N + col] = v;
      }
    }
  }
}

// ---------------- 64-row GEMM: 64x128 block, 4 waves each 64x32 -------------
// For the N=768 GEMMs (O-proj, FFN2) whose 128x128 grid is only 384 blocks
// (1.5/CU, R4-measured occupancy 15%): tile 64(M)x128(N) doubles the grid to
// 768 = 3-4 blocks/CU with no extra HBM traffic (unlike R5's split-K).
// Identical ring-3 + counted-vmcnt + asm-ds_read skeleton and XOR-chunk
// algebra as gemm_kernel; A-tile is the single-load-per-stage case (64 rows
// -> 32 LDS rows), B-stager is the R6 128-row stager verbatim.
// 3 loads/stage -> vmcnt(3). 36KB LDS -> 4 blocks/CU. fp32 out only.
__global__ __launch_bounds__(256, 4) void gemm64_kernel(
    const __bf16* __restrict__ A, const __bf16* __restrict__ Bt,
    const float* __restrict__ bias0,
    float* __restrict__ Cf, int N, int K)
{
  __shared__ __align__(16) __bf16 lA[3][32 * 64];
  __shared__ __align__(16) __bf16 lB[3][64 * 64];
  const int tid  = threadIdx.x;
  const int lane = tid & 63, wn = tid >> 6;    // wave = n-quadrant
  const int quad = lane >> 4, c16 = lane & 15;

  const int bid = blockIdx.x;
  const int xcd = bid & 7;
  const int lb  = bid >> 3;                    // 0..95
  const int mb  = xcd * 16 + (lb & 15);        // 128 M-blocks of 64 rows
  const int nb  = lb >> 4;                     // 0..5
  const size_t m0 = (size_t)mb * 64, n0 = (size_t)nb * 128;

  f32x4 acc[4][2] = {};

  // A stager (single j): slot s=tid -> lr=s>>3 (0..31), sc=s&7;
  // l=sc^(lr&7); tr=2lr+(l>>2) (0..63); gc=(l&3)*8.
  const int alr = tid >> 3, asc = tid & 7;
  const int al  = asc ^ (alr & 7);
  const int atr = (alr << 1) | (al >> 2);
  const int agc = (al & 3) * 8;
  const __bf16* Ag = A + (m0 + atr) * (size_t)K + agc;
  // B stager (two j, R6-verbatim)
  const int s0l = tid >> 3;
  const int s0c = tid & 7;
  const int l0  = s0c ^ (s0l & 7);
  const int tr0 = (s0l << 1) | (l0 >> 2);
  const int gc0 = (l0 & 3) * 8;
  const int s1l = (tid + 256) >> 3;
  const int l1  = s0c ^ (s1l & 7);
  const int tr1 = (s1l << 1) | (l1 >> 2);
  const int gc1 = (l1 & 3) * 8;
  const __bf16* Bg0 = Bt + (n0 + tr0) * (size_t)K + gc0;
  const __bf16* Bg1 = Bt + (n0 + tr1) * (size_t)K + gc1;
  const int d0 = tid * 8;

  const int nk = K >> 5;

  auto stage = [&](int t, int slot) {
    const int kof = t << 5;
    async16(Ag  + kof, &lA[slot][d0]);
    async16(Bg0 + kof, &lB[slot][d0]);
    async16(Bg1 + kof, &lB[slot][d0 + 2048]);
  };

  // readers: row r; j=r>>1; chunk=(((r&1)<<2)|quad)^(j&7); off=j*64+chunk*8
  int aoff[4], boff[2];
#pragma unroll
  for (int f = 0; f < 4; f++) {
    int ra = f * 16 + c16;                     // all waves share A rows 0..63
    int ja = ra >> 1;
    aoff[f] = ja * 64 + ((((ra & 1) << 2) | quad) ^ (ja & 7)) * 8;
  }
#pragma unroll
  for (int f = 0; f < 2; f++) {
    int rb = wn * 32 + f * 16 + c16;           // wave's 32 B-rows (cols)
    int jb = rb >> 1;
    boff[f] = jb * 64 + ((((rb & 1) << 2) | quad) ^ (jb & 7)) * 8;
  }

  stage(0, 0);
  stage(1, 1);
  asm volatile("s_waitcnt vmcnt(3)" ::: "memory");
  __builtin_amdgcn_s_barrier();
  __builtin_amdgcn_sched_barrier(0);

  int slot = 0;
  for (int t = 0; t < nk; ++t) {
    if (t + 2 < nk) {
      int ns = slot + 2; if (ns >= 3) ns -= 3;
      stage(t + 2, ns);
    }
    const __bf16* la = &lA[slot][0];
    const __bf16* lb = &lB[slot][0];
    bf16x8 af[4], bfr[2];
#pragma unroll
    for (int f = 0; f < 4; f++) af[f]  = ds_read128(la + aoff[f]);
#pragma unroll
    for (int f = 0; f < 2; f++) bfr[f] = ds_read128(lb + boff[f]);
    asm volatile("s_waitcnt lgkmcnt(0)" ::: "memory");
    __builtin_amdgcn_sched_barrier(0);
    __builtin_amdgcn_s_setprio(1);
#pragma unroll
    for (int mi = 0; mi < 4; mi++)
#pragma unroll
      for (int ni = 0; ni < 2; ni++)
        acc[mi][ni] = mfma16(af[mi], bfr[ni], acc[mi][ni]);
    __builtin_amdgcn_s_setprio(0);
    __builtin_amdgcn_sched_barrier(0);
    if (t + 2 < nk) asm volatile("s_waitcnt vmcnt(3)" ::: "memory");
    else            asm volatile("s_waitcnt vmcnt(0)" ::: "memory");
    __builtin_amdgcn_s_barrier();
    __builtin_amdgcn_sched_barrier(0);
    slot = (slot + 1 == 3) ? 0 : slot + 1;
  }

#pragma unroll
  for (int ni = 0; ni < 2; ni++) {
    int col = (int)n0 + wn * 32 + ni * 16 + c16;
    float bv = bias0[col];
#pragma unroll
    for (int mi = 0; mi < 4; mi++) {
#pragma unroll
      for (int rr = 0; rr < 4; rr++) {
        size_t row = m0 + mi * 16 + quad * 4 + rr;
        Cf[row * N + col] = acc[mi][ni][rr] + bv;
      }
    }
  }
}

// ---------------- V transpose: qkv v-section -> vt[b][h][d][s] ----------------
__global__ __launch_bounds__(256) void vtrans_kernel(
    const __bf16* __restrict__ qkv, __bf16* __restrict__ vt)
{
  int tid  = blockIdx.x * 256 + threadIdx.x;
  int d    = tid & 63;
  int rest = tid >> 6;
  int sc   = rest & 127;
  int bh   = rest >> 7;          // b*12+h
  int b = bh / Hh, h = bh % Hh;
  const __bf16* src = qkv + (size_t)(b * Ss + sc * 8) * NQKV + 2 * Ee + h * 64 + d;
  bf16x8 v;
#pragma unroll
  for (int i = 0; i < 8; i++) v[i] = src[(size_t)i * NQKV];
  *(bf16x8*)(vt + ((size_t)bh * 64 + d) * Ss + sc * 8) = v;
}

// ---------------- flash attention, no-max streaming softmax ----------------
// 8 waves / 512 threads per block, 128 q-rows per block (wave -> 16 rows).
// R7-verified: masks hoisted; V-frags loaded with K-frags; exp2+fma softmax.
__global__ __launch_bounds__(512, 6) void attn_kernel(
    const __bf16* __restrict__ qkv, const __bf16* __restrict__ vt,
    const int* __restrict__ amask, __bf16* __restrict__ out)
{
  __shared__ __align__(16) __bf16 kbuf[2][64 * 64];
  __shared__ __align__(16) __bf16 vbuf[2][64 * 64];
  __shared__ __align__(16) __bf16 plds[8][16 * 68];
  const int idx = blockIdx.x;
  const int bh = idx % 96, qi = idx / 96;     // qi in 0..7
  const int b = bh / Hh, h = bh % Hh;
  const int lane = threadIdx.x & 63, wave = threadIdx.x >> 6;
  const int quad = lane >> 4, c16 = lane & 15;
  const int q0 = qi * 128 + wave * 16;

  const __bf16* qbase = qkv + (size_t)(b * Ss + q0 + c16) * NQKV + h * 64 + quad * 8;
  bf16x8 qf0 = *(const bf16x8*)(qbase);
  bf16x8 qf1 = *(const bf16x8*)(qbase + 32);

  const int srow = threadIdx.x >> 3;          // 0..63
  const int scol = ((threadIdx.x & 7) ^ (srow & 7)) * 8;
  const __bf16* kg = qkv + (size_t)(b * Ss + srow) * NQKV + Ee + h * 64 + scol;
  const __bf16* vg = vt + ((size_t)bh * 64 + srow) * Ss + scol;

  const int sa8 = c16 & 7;
  const int rc0 = (quad ^ sa8) * 8;
  const int rc1 = ((quad + 4) ^ sa8) * 8;

  f32x4 o[4] = {};
  float lrow[4] = {0.f, 0.f, 0.f, 0.f};
  const int* mp = amask + b * Ss;
  __bf16* pw = &plds[wave][0];
  const float CE = 0.18033688f;               // 0.125 * log2(e)

  // prefetch tile 0
  async16(kg, &kbuf[0][(size_t)threadIdx.x * 8]);
  async16(vg, &vbuf[0][(size_t)threadIdx.x * 8]);

  for (int t = 0; t < 16; t++) {
    const int tb = t * 64;
    __syncthreads();
    if (t < 15) {
      const int nb = (t + 1) & 1, ntb = tb + 64;
      async16(kg + (size_t)ntb * NQKV, &kbuf[nb][(size_t)threadIdx.x * 8]);
      async16(vg + ntb,                &vbuf[nb][(size_t)threadIdx.x * 8]);
    }
    const __bf16* kb = &kbuf[t & 1][0];
    const __bf16* vb = &vbuf[t & 1][0];

    float mk2[4];
#pragma unroll
    for (int n = 0; n < 4; n++) mk2[n] = mp[tb + n * 16 + c16] ? 0.f : -1e30f;
    bf16x8 kf[8], vf[8];
#pragma unroll
    for (int n = 0; n < 4; n++) {
      kf[2*n]   = *(const bf16x8*)(kb + (n * 16 + c16) * 64 + rc0);
      kf[2*n+1] = *(const bf16x8*)(kb + (n * 16 + c16) * 64 + rc1);
    }
#pragma unroll
    for (int n = 0; n < 4; n++) {
      vf[2*n]   = *(const bf16x8*)(vb + (n * 16 + c16) * 64 + rc0);
      vf[2*n+1] = *(const bf16x8*)(vb + (n * 16 + c16) * 64 + rc1);
    }

    f32x4 s[4];
#pragma unroll
    for (int n = 0; n < 4; n++) {
      f32x4 z = {};
      z = mfma16(qf0, kf[2*n], z);
      s[n] = mfma16(qf1, kf[2*n+1], z);
    }

#pragma unroll
    for (int rr = 0; rr < 4; rr++) {
      float p0 = fexp2(fmaf(s[0][rr], CE, mk2[0]));   // e^(s/8), masked->0
      float p1 = fexp2(fmaf(s[1][rr], CE, mk2[1]));
      float p2 = fexp2(fmaf(s[2][rr], CE, mk2[2]));
      float p3 = fexp2(fmaf(s[3][rr], CE, mk2[3]));
      lrow[rr] += (p0 + p1) + (p2 + p3);
      int prow = (quad * 4 + rr) * 68;
      pw[prow + 0  + c16] = (__bf16)p0;
      pw[prow + 16 + c16] = (__bf16)p1;
      pw[prow + 32 + c16] = (__bf16)p2;
      pw[prow + 48 + c16] = (__bf16)p3;
    }

    // P: C-layout -> A-layout via per-wave LDS roundtrip (same-wave, no barrier)
    bf16x8 pf0 = *(const bf16x8*)(pw + c16 * 68 + quad * 8);
    bf16x8 pf1 = *(const bf16x8*)(pw + c16 * 68 + 32 + quad * 8);
#pragma unroll
    for (int ni = 0; ni < 4; ni++) {
      o[ni] = mfma16(pf0, vf[2*ni],   o[ni]);
      o[ni] = mfma16(pf1, vf[2*ni+1], o[ni]);
    }
  }

  // row-sum reduction across the 16 lanes holding this row's columns
#pragma unroll
  for (int rr = 0; rr < 4; rr++) {
    float sr = lrow[rr];
    sr += __shfl_xor(sr, 1);
    sr += __shfl_xor(sr, 2);
    sr += __shfl_xor(sr, 4);
    sr += __shfl_xor(sr, 8);
    float inv = 1.f / sr;
    size_t row = (size_t)(b * Ss + q0 + quad * 4 + rr) * Ee + h * 64;
    out[row + 0  + c16] = (__bf16)(o[0][rr] * inv);
    out[row + 16 + c16] = (__bf16)(o[1][rr] * inv);
    out[row + 32 + c16] = (__bf16)(o[2][rr] * inv);
    out[row + 48 + c16] = (__bf16)(o[3][rr] * inv);
  }
}

// ---------------- residual add + layernorm ----------------
__global__ __launch_bounds__(256) void add_ln_kernel(
    const float* __restrict__ xin, const float* __restrict__ tmp,
    const float* __restrict__ g, const float* __restrict__ beta,
    float* __restrict__ xout, __bf16* __restrict__ xbout)
{
  __shared__ float red[8];
  size_t base = (size_t)blockIdx.x * Ee;
  float hv[3], s = 0.f, sq = 0.f;
#pragma unroll
  for (int i = 0; i < 3; i++) {
    int e = threadIdx.x + i * 256;
    hv[i] = xin[base + e] + tmp[base + e];
    s += hv[i]; sq += hv[i] * hv[i];
  }
#pragma unroll
  for (int m = 1; m < 64; m <<= 1) { s += __shfl_xor(s, m); sq += __shfl_xor(sq, m); }
  int wave = threadIdx.x >> 6;
  if ((threadIdx.x & 63) == 0) { red[wave] = s; red[4 + wave] = sq; }
  __syncthreads();
  s  = red[0] + red[1] + red[2] + red[3];
  sq = red[4] + red[5] + red[6] + red[7];
  float mean = s * (1.f / Ee);
  float var  = sq * (1.f / Ee) - mean * mean;
  float rstd = rsqrtf(var + 1e-5f);
#pragma unroll
  for (int i = 0; i < 3; i++) {
    int e = threadIdx.x + i * 256;
    float v = (hv[i] - mean) * rstd * g[e] + beta[e];
    xout[base + e]  = v;
    xbout[base + e] = (__bf16)v;
  }
}

// ---------------- mean pool (stage 1) ----------------
__global__ __launch_bounds__(256) void pool1_kernel(
    const float* __restrict__ x, float* __restrict__ partial)
{
  int b = blockIdx.x, chunk = blockIdx.y;
  float acc[3] = {0.f, 0.f, 0.f};
  for (int s = chunk * 64; s < chunk * 64 + 64; s++) {
#pragma unroll
    for (int i = 0; i < 3; i++) {
      int e = threadIdx.x + i * 256;
      acc[i] += x[((size_t)b * Ss + s) * Ee + e];
    }
  }
#pragma unroll
  for (int i = 0; i < 3; i++) {
    int e = threadIdx.x + i * 256;
    partial[((size_t)b * 16 + chunk) * Ee + e] = acc[i];
  }
}

// ---------------- pool reduce + classifier ----------------
__global__ __launch_bounds__(256) void pool2_kernel(
    const float* __restrict__ partial, const float* __restrict__ Wc,
    const float* __restrict__ bc, float* __restrict__ out)
{
  __shared__ float red[8];
  int b = blockIdx.x;
  float p0 = 0.f, p1 = 0.f;
#pragma unroll
  for (int i = 0; i < 3; i++) {
    int e = threadIdx.x + i * 256;
    float pe_ = 0.f;
#pragma unroll
    for (int c = 0; c < 16; c++) pe_ += partial[((size_t)b * 16 + c) * Ee + e];
    pe_ *= (1.f / Ss);
    p0 += pe_ * Wc[e * 2 + 0];
    p1 += pe_ * Wc[e * 2 + 1];
  }
#pragma unroll
  for (int m = 1; m < 64; m <<= 1) { p0 += __shfl_xor(p0, m); p1 += __shfl_xor(p1, m); }
  int wave = threadIdx.x >> 6;
  if ((threadIdx.x & 63) == 0) { red[wave] = p0; red[4 + wave] = p1; }
  __syncthreads();
  if (threadIdx.x == 0) {
    out[b * 2 + 0] = red[0] + red[1] + red[2] + red[3] + bc[0];
    out[b * 2 + 1] = red[4] + red[5] + red[6] + red[7] + bc[1];
  }
}

extern "C" void kernel_launch(void* const* d_in, const int* in_sizes, int n_in,
                              void* d_out, int out_size, void* d_ws, size_t ws_size,
                              hipStream_t stream) {
  const int*   ids   = (const int*)  d_in[0];
  const int*   amask = (const int*)  d_in[1];
  const float* emb   = (const float*)d_in[2];
  const float* pe    = (const float*)d_in[3];
  const float* Wq    = (const float*)d_in[4];
  const float* bq    = (const float*)d_in[5];
  const float* Wk    = (const float*)d_in[6];
  const float* bk    = (const float*)d_in[7];
  const float* Wv    = (const float*)d_in[8];
  const float* bv    = (const float*)d_in[9];
  const float* Wo    = (const float*)d_in[10];
  const float* bo    = (const float*)d_in[11];
  const float* ln1g  = (const float*)d_in[12];
  const float* ln1b  = (const float*)d_in[13];
  const float* W1    = (const float*)d_in[14];
  const float* b1    = (const float*)d_in[15];
  const float* W2    = (const float*)d_in[16];
  const float* b2    = (const float*)d_in[17];
  const float* ln2g  = (const float*)d_in[18];
  const float* ln2b  = (const float*)d_in[19];
  const float* Wc    = (const float*)d_in[20];
  const float* bc    = (const float*)d_in[21];
  float* outp = (float*)d_out;

  char* p = (char*)d_ws;
  auto alloc = [&](size_t bytes) { char* r = p; p += (bytes + 255) & ~(size_t)255; return r; };
  float*  x     = (float*) alloc((size_t)TOK * Ee * 4);
  __bf16* xb    = (__bf16*)alloc((size_t)TOK * Ee * 2);
  float*  tmp   = (float*) alloc((size_t)TOK * Ee * 4);
  __bf16* attn  = (__bf16*)alloc((size_t)TOK * Ee * 2);
  char*   r1    = alloc((size_t)TOK * Ff * 2);          // union: [qkv|vt] / h1
  __bf16* qkv   = (__bf16*)r1;
  __bf16* vt    = (__bf16*)(r1 + (size_t)TOK * NQKV * 2);
  __bf16* h1    = (__bf16*)r1;
  __bf16* wqkvt = (__bf16*)alloc((size_t)Ll * NQKV * Ee * 2);
  __bf16* wot   = (__bf16*)alloc((size_t)Ll * Ee * Ee * 2);
  __bf16* w1t   = (__bf16*)alloc((size_t)Ll * Ff * Ee * 2);
  __bf16* w2t   = (__bf16*)alloc((size_t)Ll * Ee * Ff * 2);
  float*  part  = (float*) alloc((size_t)Bb * 16 * Ee * 4);

  // embedding
  embed_kernel<<<TOK, 256, 0, stream>>>(ids, emb, pe, x, xb);

  // weight prep (all layers at once)
  transpose_w_kernel<<<dim3(Ee/32, Ee/32, Ll), 256, 0, stream>>>(
      Wq, wqkvt,                         Ee, Ee, (size_t)Ee*Ee, (size_t)NQKV*Ee);
  transpose_w_kernel<<<dim3(Ee/32, Ee/32, Ll), 256, 0, stream>>>(
      Wk, wqkvt + (size_t)Ee*Ee,         Ee, Ee, (size_t)Ee*Ee, (size_t)NQKV*Ee);
  transpose_w_kernel<<<dim3(Ee/32, Ee/32, Ll), 256, 0, stream>>>(
      Wv, wqkvt + (size_t)2*Ee*Ee,       Ee, Ee, (size_t)Ee*Ee, (size_t)NQKV*Ee);
  transpose_w_kernel<<<dim3(Ee/32, Ee/32, Ll), 256, 0, stream>>>(
      Wo, wot,                           Ee, Ee, (size_t)Ee*Ee, (size_t)Ee*Ee);
  transpose_w_kernel<<<dim3(Ff/32, Ee/32, Ll), 256, 0, stream>>>(
      W1, w1t,                           Ee, Ff, (size_t)Ee*Ff, (size_t)Ff*Ee);
  transpose_w_kernel<<<dim3(Ee/32, Ff/32, Ll), 256, 0, stream>>>(
      W2, w2t,                           Ff, Ee, (size_t)Ff*Ee, (size_t)Ee*Ff);

  for (int l = 0; l < Ll; l++) {
    // QKV projection (packed N=2304), bf16 out (R6-verified config)
    gemm_kernel<true, false><<<64 * (NQKV/128), 256, 0, stream>>>(
        xb, wqkvt + (size_t)l*NQKV*Ee,
        bq + l*Ee, bk + l*Ee, bv + l*Ee, Ee,
        nullptr, qkv, TOK, NQKV, Ee);
    // V -> [b,h,d,s]
    vtrans_kernel<<<3072, 256, 0, stream>>>(qkv, vt);
    // flash attention: 8 waves/block, 128 q-rows per block
    attn_kernel<<<768, 512, 0, stream>>>(qkv, vt, amask, attn);
    // O projection, fp32 out: 64x128 tiles, grid 768 (3-4 blocks/CU)
    gemm64_kernel<<<768, 256, 0, stream>>>(
        attn, wot + (size_t)l*Ee*Ee, bo + l*Ee, tmp, Ee, Ee);
    // x = LN(x + o)
    add_ln_kernel<<<TOK, 256, 0, stream>>>(x, tmp, ln1g + l*Ee, ln1b + l*Ee, x, xb);
    // FFN1 + relu, bf16 out (R6-verified config)
    gemm_kernel<true, true><<<64 * (Ff/128), 256, 0, stream>>>(
        xb, w1t + (size_t)l*Ff*Ee,
        b1 + l*Ff, b1 + l*Ff, b1 + l*Ff, Ff,
        nullptr, h1, TOK, Ff, Ee);
    // FFN2, fp32 out: 64x128 tiles, grid 768
    gemm64_kernel<<<768, 256, 0, stream>>>(
        h1, w2t + (size_t)l*Ee*Ff, b2 + l*Ee, tmp, Ee, Ff);
    // x = LN(x + ffn)
    add_ln_kernel<<<TOK, 256, 0, stream>>>(x, tmp, ln2g + l*Ee, ln2b + l*Ee, x, xb);
  }

  // mean pool + classifier
  pool1_kernel<<<dim3(Bb, 16), 256, 0, stream>>>(x, part);
  pool2_kernel<<<Bb, 256, 0, stream>>>(part, Wc, bc, outp);
}

// Round 9
// 1898.524 us; speedup vs baseline: 1.0475x; 1.0475x over previous
//
#include <hip/hip_runtime.h>

typedef __bf16 bf16x8 __attribute__((ext_vector_type(8)));
typedef float  f32x4  __attribute__((ext_vector_type(4)));

constexpr int Bb = 8, Ss = 1024, Ee = 768, Hh = 12, Ll = 6, Ff = 3072;
constexpr int TOK  = Bb * Ss;      // 8192
constexpr int NQKV = 3 * Ee;       // 2304

static __device__ __forceinline__ f32x4 mfma16(bf16x8 a, bf16x8 b, f32x4 c) {
  return __builtin_amdgcn_mfma_f32_16x16x32_bf16(a, b, c, 0, 0, 0);
}

// async global->LDS, 16B per lane. LDS dest is wave-uniform base + lane*16.
static __device__ __forceinline__ void async16(const void* g, void* l) {
  __builtin_amdgcn_global_load_lds(
      (const __attribute__((address_space(1))) unsigned int*)g,
      (__attribute__((address_space(3))) unsigned int*)l, 16, 0, 0);
}

// inline-asm ds_read_b128: invisible to the compiler's vmcnt alias tracking,
// so it cannot conservatively insert s_waitcnt vmcnt(0) before it (which
// would defeat the counted-vmcnt ring pipeline). MUST be followed by
// lgkmcnt(0) + sched_barrier(0) before any consumer (rule 18).
static __device__ __forceinline__ bf16x8 ds_read128(const __bf16* p) {
  bf16x8 r;
  unsigned a = (unsigned)(size_t)p;      // LDS pointers are 32-bit offsets
  asm volatile("ds_read_b128 %0, %1" : "=v"(r) : "v"(a));
  return r;
}

// raw v_exp_f32 (computes 2^x); HW-interlocked on CDNA.
static __device__ __forceinline__ float fexp2(float x) {
  float r; asm("v_exp_f32 %0, %1" : "=v"(r) : "v"(x)); return r;
}

// ---------------- embedding + positional encoding ----------------
__global__ __launch_bounds__(256) void embed_kernel(
    const int* __restrict__ ids, const float* __restrict__ emb,
    const float* __restrict__ pe, float* __restrict__ x, __bf16* __restrict__ xb)
{
  int tok = blockIdx.x;
  int s   = tok & (Ss - 1);
  int id  = ids[tok];
  const float* er = emb + (size_t)id * Ee;
  const float* pr = pe  + (size_t)s  * Ee;
  size_t base = (size_t)tok * Ee;
#pragma unroll
  for (int i = 0; i < 3; i++) {
    int e = threadIdx.x + i * 256;
    float v = er[e] + pr[e];
    x[base + e]  = v;
    xb[base + e] = (__bf16)v;
  }
}

// ---------------- weight transpose fp32 (K x N) -> bf16 (N x K) ----------------
__global__ __launch_bounds__(256) void transpose_w_kernel(
    const float* __restrict__ src, __bf16* __restrict__ dst,
    int K, int N, size_t sls, size_t dls)
{
  __shared__ float t[32][33];
  src += (size_t)blockIdx.z * sls;
  dst += (size_t)blockIdx.z * dls;
  int n0 = blockIdx.x * 32, k0 = blockIdx.y * 32;
  int c = threadIdx.x & 31, r0 = threadIdx.x >> 5;
#pragma unroll
  for (int rr = 0; rr < 32; rr += 8)
    t[r0 + rr][c] = src[(size_t)(k0 + r0 + rr) * N + n0 + c];
  __syncthreads();
#pragma unroll
  for (int rr = 0; rr < 32; rr += 8)
    dst[(size_t)(n0 + r0 + rr) * K + k0 + c] = (__bf16)t[c][r0 + rr];
}

// ---------------- small GEMM (R6-verified): 128x128 block, waves 64x64 ------
// Ring-3 LDS + counted vmcnt + asm ds_read. Used for QKV and FFN1
// (large-N GEMMs where grid 64*(N/128) gives >= 12 waves/CU already).
template<bool OUT_BF16, bool RELU>
__global__ __launch_bounds__(256, 3) void gemm_kernel(
    const __bf16* __restrict__ A, const __bf16* __restrict__ Bt,
    const float* __restrict__ bias0, const float* __restrict__ bias1,
    const float* __restrict__ bias2, int bseg,
    float* __restrict__ Cf, __bf16* __restrict__ Cb, int M, int N, int K)
{
  __shared__ __align__(16) __bf16 lA[3][64 * 64];
  __shared__ __align__(16) __bf16 lB[3][64 * 64];
  const int tid  = threadIdx.x;
  const int wave = tid >> 6, lane = tid & 63;
  const int quad = lane >> 4, c16 = lane & 15;
  const int wm = wave >> 1, wn = wave & 1;

  const int bid = blockIdx.x;
  const int xcd = bid & 7;
  const int lb  = bid >> 3;
  const int mb  = xcd * 8 + (lb & 7);   // M/128 == 64 always
  const int nb  = lb >> 3;
  const size_t m0 = (size_t)mb * 128, n0 = (size_t)nb * 128;

  f32x4 acc[4][4] = {};

  const int s0l = tid >> 3;
  const int s0c = tid & 7;
  const int l0  = s0c ^ (s0l & 7);
  const int tr0 = (s0l << 1) | (l0 >> 2);
  const int gc0 = (l0 & 3) * 8;
  const int s1l = (tid + 256) >> 3;
  const int l1  = s0c ^ (s1l & 7);
  const int tr1 = (s1l << 1) | (l1 >> 2);
  const int gc1 = (l1 & 3) * 8;

  const __bf16* Ag0 = A  + (m0 + tr0) * K + gc0;
  const __bf16* Ag1 = A  + (m0 + tr1) * K + gc1;
  const __bf16* Bg0 = Bt + (n0 + tr0) * K + gc0;
  const __bf16* Bg1 = Bt + (n0 + tr1) * K + gc1;
  const int d0 = tid * 8;

  const int nk = K >> 5;

  auto stage = [&](int t, int slot) {
    const int kof = t << 5;
    async16(Ag0 + kof, &lA[slot][d0]);
    async16(Ag1 + kof, &lA[slot][d0 + 2048]);
    async16(Bg0 + kof, &lB[slot][d0]);
    async16(Bg1 + kof, &lB[slot][d0 + 2048]);
  };

  int aoff[4], boff[4];
#pragma unroll
  for (int f = 0; f < 4; f++) {
    int ra = wm * 64 + f * 16 + c16;
    int ja = ra >> 1;
    aoff[f] = ja * 64 + (((((ra & 1) << 2) | quad)) ^ (ja & 7)) * 8;
    int rb = wn * 64 + f * 16 + c16;
    int jb = rb >> 1;
    boff[f] = jb * 64 + (((((rb & 1) << 2) | quad)) ^ (jb & 7)) * 8;
  }

  stage(0, 0);
  stage(1, 1);
  asm volatile("s_waitcnt vmcnt(4)" ::: "memory");
  __builtin_amdgcn_s_barrier();
  __builtin_amdgcn_sched_barrier(0);

  int slot = 0;
  for (int t = 0; t < nk; ++t) {
    if (t + 2 < nk) {
      int ns = slot + 2; if (ns >= 3) ns -= 3;
      stage(t + 2, ns);
    }
    const __bf16* la = &lA[slot][0];
    const __bf16* lb = &lB[slot][0];
    bf16x8 af[4], bfr[4];
#pragma unroll
    for (int f = 0; f < 4; f++) af[f]  = ds_read128(la + aoff[f]);
#pragma unroll
    for (int f = 0; f < 4; f++) bfr[f] = ds_read128(lb + boff[f]);
    asm volatile("s_waitcnt lgkmcnt(0)" ::: "memory");
    __builtin_amdgcn_sched_barrier(0);
    __builtin_amdgcn_s_setprio(1);
#pragma unroll
    for (int mi = 0; mi < 4; mi++)
#pragma unroll
      for (int ni = 0; ni < 4; ni++)
        acc[mi][ni] = mfma16(af[mi], bfr[ni], acc[mi][ni]);
    __builtin_amdgcn_s_setprio(0);
    __builtin_amdgcn_sched_barrier(0);
    if (t + 2 < nk) asm volatile("s_waitcnt vmcnt(4)" ::: "memory");
    else            asm volatile("s_waitcnt vmcnt(0)" ::: "memory");
    __builtin_amdgcn_s_barrier();
    __builtin_amdgcn_sched_barrier(0);
    slot = (slot + 1 == 3) ? 0 : slot + 1;
  }

#pragma unroll
  for (int ni = 0; ni < 4; ni++) {
    int col = (int)n0 + wn * 64 + ni * 16 + c16;
    const float* bp = bias0;
    int cc = col;
    if (cc >= bseg) { bp = bias1; cc -= bseg; }
    if (cc >= bseg) { bp = bias2; cc -= bseg; }
    float bv = bp[cc];
#pragma unroll
    for (int mi = 0; mi < 4; mi++) {
#pragma unroll
      for (int rr = 0; rr < 4; rr++) {
        size_t row = m0 + wm * 64 + mi * 16 + quad * 4 + rr;
        float v = acc[mi][ni][rr] + bv;
        if (RELU) v = fmaxf(v, 0.f);
        if (OUT_BF16) Cb[row * N + col] = (__bf16)v;
        else          Cf[row * N + col] = v;
      }
    }
  }
}

// ---------------- 8-wave GEMM: 128x128 block, 512 threads, waves 32x64 ------
// For the N=768 GEMMs (O-proj, FFN2) whose grid is only 384 blocks: same
// 128x128 tile (same FETCH profile - gemm64's B-refetch was the R8 mistake)
// but 8 waves/block -> 384*8/256 = 12 resident waves/CU (vs 6 with 4-wave),
// doubling TLP with zero extra traffic. Identical ring-3 + counted-vmcnt +
// asm-ds_read skeleton and XOR-chunk algebra; stager is 1 async16/thread per
// operand (512 slots = full 128x32 tile); 2 loads/stage -> vmcnt(2).
// Wave grid 4x2: each wave 32(M)x64(N), acc 2x4, 8 MFMA/K-step.
// 48KB LDS -> 3 blocks/CU cap (not binding at grid 384). fp32 out.
__global__ __launch_bounds__(512, 6) void gemm8w_kernel(
    const __bf16* __restrict__ A, const __bf16* __restrict__ Bt,
    const float* __restrict__ bias0,
    float* __restrict__ Cf, int N, int K)
{
  __shared__ __align__(16) __bf16 lA[3][64 * 64];
  __shared__ __align__(16) __bf16 lB[3][64 * 64];
  const int tid  = threadIdx.x;
  const int wave = tid >> 6, lane = tid & 63;
  const int quad = lane >> 4, c16 = lane & 15;
  const int wm = wave >> 1, wn = wave & 1;   // 4x2 wave grid

  const int bid = blockIdx.x;
  const int xcd = bid & 7;
  const int lb  = bid >> 3;
  const int mb  = xcd * 8 + (lb & 7);        // 64 M-blocks
  const int nb  = lb >> 3;                   // 0..5
  const size_t m0 = (size_t)mb * 128, n0 = (size_t)nb * 128;

  f32x4 acc[2][4] = {};

  // stager: slot s = tid (0..511); lr=s>>3 (0..63), sc=s&7; l=sc^(lr&7);
  // tr=2lr+(l>>2) (0..127); gc=(l&3)*8. One async16 per operand per thread.
  const int slr = tid >> 3, ssc = tid & 7;
  const int sl  = ssc ^ (slr & 7);
  const int str = (slr << 1) | (sl >> 2);
  const int sgc = (sl & 3) * 8;
  const __bf16* Ag = A  + (m0 + str) * (size_t)K + sgc;
  const __bf16* Bg = Bt + (n0 + str) * (size_t)K + sgc;
  const int d0 = tid * 8;

  const int nk = K >> 5;

  auto stage = [&](int t, int slot) {
    const int kof = t << 5;
    async16(Ag + kof, &lA[slot][d0]);
    async16(Bg + kof, &lB[slot][d0]);
  };

  // readers: row r; j=r>>1; chunk=(((r&1)<<2)|quad)^(j&7); off=j*64+chunk*8
  int aoff[2], boff[4];
#pragma unroll
  for (int f = 0; f < 2; f++) {
    int ra = wm * 32 + f * 16 + c16;
    int ja = ra >> 1;
    aoff[f] = ja * 64 + ((((ra & 1) << 2) | quad) ^ (ja & 7)) * 8;
  }
#pragma unroll
  for (int f = 0; f < 4; f++) {
    int rb = wn * 64 + f * 16 + c16;
    int jb = rb >> 1;
    boff[f] = jb * 64 + ((((rb & 1) << 2) | quad) ^ (jb & 7)) * 8;
  }

  stage(0, 0);
  stage(1, 1);
  asm volatile("s_waitcnt vmcnt(2)" ::: "memory");
  __builtin_amdgcn_s_barrier();
  __builtin_amdgcn_sched_barrier(0);

  int slot = 0;
  for (int t = 0; t < nk; ++t) {
    if (t + 2 < nk) {
      int ns = slot + 2; if (ns >= 3) ns -= 3;
      stage(t + 2, ns);
    }
    const __bf16* la = &lA[slot][0];
    const __bf16* lb = &lB[slot][0];
    bf16x8 af[2], bfr[4];
#pragma unroll
    for (int f = 0; f < 2; f++) af[f]  = ds_read128(la + aoff[f]);
#pragma unroll
    for (int f = 0; f < 4; f++) bfr[f] = ds_read128(lb + boff[f]);
    asm volatile("s_waitcnt lgkmcnt(0)" ::: "memory");
    __builtin_amdgcn_sched_barrier(0);
    __builtin_amdgcn_s_setprio(1);
#pragma unroll
    for (int mi = 0; mi < 2; mi++)
#pragma unroll
      for (int ni = 0; ni < 4; ni++)
        acc[mi][ni] = mfma16(af[mi], bfr[ni], acc[mi][ni]);
    __builtin_amdgcn_s_setprio(0);
    __builtin_amdgcn_sched_barrier(0);
    if (t + 2 < nk) asm volatile("s_waitcnt vmcnt(2)" ::: "memory");
    else            asm volatile("s_waitcnt vmcnt(0)" ::: "memory");
    __builtin_amdgcn_s_barrier();
    __builtin_amdgcn_sched_barrier(0);
    slot = (slot + 1 == 3) ? 0 : slot + 1;
  }

#pragma unroll
  for (int ni = 0; ni < 4; ni++) {
    int col = (int)n0 + wn * 64 + ni * 16 + c16;
    float bv = bias0[col];
#pragma unroll
    for (int mi = 0; mi < 2; mi++) {
#pragma unroll
      for (int rr = 0; rr < 4; rr++) {
        size_t row = m0 + wm * 32 + mi * 16 + quad * 4 + rr;
        Cf[row * N + col] = acc[mi][ni][rr] + bv;
      }
    }
  }
}

// ---------------- V transpose: qkv v-section -> vt[b][h][d][s] ----------------
__global__ __launch_bounds__(256) void vtrans_kernel(
    const __bf16* __restrict__ qkv, __bf16* __restrict__ vt)
{
  int tid  = blockIdx.x * 256 + threadIdx.x;
  int d    = tid & 63;
  int rest = tid >> 6;
  int sc   = rest & 127;
  int bh   = rest >> 7;          // b*12+h
  int b = bh / Hh, h = bh % Hh;
  const __bf16* src = qkv + (size_t)(b * Ss + sc * 8) * NQKV + 2 * Ee + h * 64 + d;
  bf16x8 v;
#pragma unroll
  for (int i = 0; i < 8; i++) v[i] = src[(size_t)i * NQKV];
  *(bf16x8*)(vt + ((size_t)bh * 64 + d) * Ss + sc * 8) = v;
}

// ---------------- flash attention, no-max streaming softmax ----------------
// 8 waves / 512 threads per block, 128 q-rows per block (wave -> 16 rows).
// R7-verified: masks hoisted; V-frags loaded with K-frags; exp2+fma softmax.
__global__ __launch_bounds__(512, 6) void attn_kernel(
    const __bf16* __restrict__ qkv, const __bf16* __restrict__ vt,
    const int* __restrict__ amask, __bf16* __restrict__ out)
{
  __shared__ __align__(16) __bf16 kbuf[2][64 * 64];
  __shared__ __align__(16) __bf16 vbuf[2][64 * 64];
  __shared__ __align__(16) __bf16 plds[8][16 * 68];
  const int idx = blockIdx.x;
  const int bh = idx % 96, qi = idx / 96;     // qi in 0..7
  const int b = bh / Hh, h = bh % Hh;
  const int lane = threadIdx.x & 63, wave = threadIdx.x >> 6;
  const int quad = lane >> 4, c16 = lane & 15;
  const int q0 = qi * 128 + wave * 16;

  const __bf16* qbase = qkv + (size_t)(b * Ss + q0 + c16) * NQKV + h * 64 + quad * 8;
  bf16x8 qf0 = *(const bf16x8*)(qbase);
  bf16x8 qf1 = *(const bf16x8*)(qbase + 32);

  const int srow = threadIdx.x >> 3;          // 0..63
  const int scol = ((threadIdx.x & 7) ^ (srow & 7)) * 8;
  const __bf16* kg = qkv + (size_t)(b * Ss + srow) * NQKV + Ee + h * 64 + scol;
  const __bf16* vg = vt + ((size_t)bh * 64 + srow) * Ss + scol;

  const int sa8 = c16 & 7;
  const int rc0 = (quad ^ sa8) * 8;
  const int rc1 = ((quad + 4) ^ sa8) * 8;

  f32x4 o[4] = {};
  float lrow[4] = {0.f, 0.f, 0.f, 0.f};
  const int* mp = amask + b * Ss;
  __bf16* pw = &plds[wave][0];
  const float CE = 0.18033688f;               // 0.125 * log2(e)

  // prefetch tile 0
  async16(kg, &kbuf[0][(size_t)threadIdx.x * 8]);
  async16(vg, &vbuf[0][(size_t)threadIdx.x * 8]);

  for (int t = 0; t < 16; t++) {
    const int tb = t * 64;
    __syncthreads();
    if (t < 15) {
      const int nb = (t + 1) & 1, ntb = tb + 64;
      async16(kg + (size_t)ntb * NQKV, &kbuf[nb][(size_t)threadIdx.x * 8]);
      async16(vg + ntb,                &vbuf[nb][(size_t)threadIdx.x * 8]);
    }
    const __bf16* kb = &kbuf[t & 1][0];
    const __bf16* vb = &vbuf[t & 1][0];

    float mk2[4];
#pragma unroll
    for (int n = 0; n < 4; n++) mk2[n] = mp[tb + n * 16 + c16] ? 0.f : -1e30f;
    bf16x8 kf[8], vf[8];
#pragma unroll
    for (int n = 0; n < 4; n++) {
      kf[2*n]   = *(const bf16x8*)(kb + (n * 16 + c16) * 64 + rc0);
      kf[2*n+1] = *(const bf16x8*)(kb + (n * 16 + c16) * 64 + rc1);
    }
#pragma unroll
    for (int n = 0; n < 4; n++) {
      vf[2*n]   = *(const bf16x8*)(vb + (n * 16 + c16) * 64 + rc0);
      vf[2*n+1] = *(const bf16x8*)(vb + (n * 16 + c16) * 64 + rc1);
    }

    f32x4 s[4];
#pragma unroll
    for (int n = 0; n < 4; n++) {
      f32x4 z = {};
      z = mfma16(qf0, kf[2*n], z);
      s[n] = mfma16(qf1, kf[2*n+1], z);
    }

#pragma unroll
    for (int rr = 0; rr < 4; rr++) {
      float p0 = fexp2(fmaf(s[0][rr], CE, mk2[0]));   // e^(s/8), masked->0
      float p1 = fexp2(fmaf(s[1][rr], CE, mk2[1]));
      float p2 = fexp2(fmaf(s[2][rr], CE, mk2[2]));
      float p3 = fexp2(fmaf(s[3][rr], CE, mk2[3]));
      lrow[rr] += (p0 + p1) + (p2 + p3);
      int prow = (quad * 4 + rr) * 68;
      pw[prow + 0  + c16] = (__bf16)p0;
      pw[prow + 16 + c16] = (__bf16)p1;
      pw[prow + 32 + c16] = (__bf16)p2;
      pw[prow + 48 + c16] = (__bf16)p3;
    }

    // P: C-layout -> A-layout via per-wave LDS roundtrip (same-wave, no barrier)
    bf16x8 pf0 = *(const bf16x8*)(pw + c16 * 68 + quad * 8);
    bf16x8 pf1 = *(const bf16x8*)(pw + c16 * 68 + 32 + quad * 8);
#pragma unroll
    for (int ni = 0; ni < 4; ni++) {
      o[ni] = mfma16(pf0, vf[2*ni],   o[ni]);
      o[ni] = mfma16(pf1, vf[2*ni+1], o[ni]);
    }
  }

  // row-sum reduction across the 16 lanes holding this row's columns
#pragma unroll
  for (int rr = 0; rr < 4; rr++) {
    float sr = lrow[rr];
    sr += __shfl_xor(sr, 1);
    sr += __shfl_xor(sr, 2);
    sr += __shfl_xor(sr, 4);
    sr += __shfl_xor(sr, 8);
    float inv = 1.f / sr;
    size_t row = (size_t)(b * Ss + q0 + quad * 4 + rr) * Ee + h * 64;
    out[row + 0  + c16] = (__bf16)(o[0][rr] * inv);
    out[row + 16 + c16] = (__bf16)(o[1][rr] * inv);
    out[row + 32 + c16] = (__bf16)(o[2][rr] * inv);
    out[row + 48 + c16] = (__bf16)(o[3][rr] * inv);
  }
}

// ---------------- residual add + layernorm ----------------
__global__ __launch_bounds__(256) void add_ln_kernel(
    const float* __restrict__ xin, const float* __restrict__ tmp,
    const float* __restrict__ g, const float* __restrict__ beta,
    float* __restrict__ xout, __bf16* __restrict__ xbout)
{
  __shared__ float red[8];
  size_t base = (size_t)blockIdx.x * Ee;
  float hv[3], s = 0.f, sq = 0.f;
#pragma unroll
  for (int i = 0; i < 3; i++) {
    int e = threadIdx.x + i * 256;
    hv[i] = xin[base + e] + tmp[base + e];
    s += hv[i]; sq += hv[i] * hv[i];
  }
#pragma unroll
  for (int m = 1; m < 64; m <<= 1) { s += __shfl_xor(s, m); sq += __shfl_xor(sq, m); }
  int wave = threadIdx.x >> 6;
  if ((threadIdx.x & 63) == 0) { red[wave] = s; red[4 + wave] = sq; }
  __syncthreads();
  s  = red[0] + red[1] + red[2] + red[3];
  sq = red[4] + red[5] + red[6] + red[7];
  float mean = s * (1.f / Ee);
  float var  = sq * (1.f / Ee) - mean * mean;
  float rstd = rsqrtf(var + 1e-5f);
#pragma unroll
  for (int i = 0; i < 3; i++) {
    int e = threadIdx.x + i * 256;
    float v = (hv[i] - mean) * rstd * g[e] + beta[e];
    xout[base + e]  = v;
    xbout[base + e] = (__bf16)v;
  }
}

// ---------------- mean pool (stage 1) ----------------
__global__ __launch_bounds__(256) void pool1_kernel(
    const float* __restrict__ x, float* __restrict__ partial)
{
  int b = blockIdx.x, chunk = blockIdx.y;
  float acc[3] = {0.f, 0.f, 0.f};
  for (int s = chunk * 64; s < chunk * 64 + 64; s++) {
#pragma unroll
    for (int i = 0; i < 3; i++) {
      int e = threadIdx.x + i * 256;
      acc[i] += x[((size_t)b * Ss + s) * Ee + e];
    }
  }
#pragma unroll
  for (int i = 0; i < 3; i++) {
    int e = threadIdx.x + i * 256;
    partial[((size_t)b * 16 + chunk) * Ee + e] = acc[i];
  }
}

// ---------------- pool reduce + classifier ----------------
__global__ __launch_bounds__(256) void pool2_kernel(
    const float* __restrict__ partial, const float* __restrict__ Wc,
    const float* __restrict__ bc, float* __restrict__ out)
{
  __shared__ float red[8];
  int b = blockIdx.x;
  float p0 = 0.f, p1 = 0.f;
#pragma unroll
  for (int i = 0; i < 3; i++) {
    int e = threadIdx.x + i * 256;
    float pe_ = 0.f;
#pragma unroll
    for (int c = 0; c < 16; c++) pe_ += partial[((size_t)b * 16 + c) * Ee + e];
    pe_ *= (1.f / Ss);
    p0 += pe_ * Wc[e * 2 + 0];
    p1 += pe_ * Wc[e * 2 + 1];
  }
#pragma unroll
  for (int m = 1; m < 64; m <<= 1) { p0 += __shfl_xor(p0, m); p1 += __shfl_xor(p1, m); }
  int wave = threadIdx.x >> 6;
  if ((threadIdx.x & 63) == 0) { red[wave] = p0; red[4 + wave] = p1; }
  __syncthreads();
  if (threadIdx.x == 0) {
    out[b * 2 + 0] = red[0] + red[1] + red[2] + red[3] + bc[0];
    out[b * 2 + 1] = red[4] + red[5] + red[6] + red[7] + bc[1];
  }
}

extern "C" void kernel_launch(void* const* d_in, const int* in_sizes, int n_in,
                              void* d_out, int out_size, void* d_ws, size_t ws_size,
                              hipStream_t stream) {
  const int*   ids   = (const int*)  d_in[0];
  const int*   amask = (const int*)  d_in[1];
  const float* emb   = (const float*)d_in[2];
  const float* pe    = (const float*)d_in[3];
  const float* Wq    = (const float*)d_in[4];
  const float* bq    = (const float*)d_in[5];
  const float* Wk    = (const float*)d_in[6];
  const float* bk    = (const float*)d_in[7];
  const float* Wv    = (const float*)d_in[8];
  const float* bv    = (const float*)d_in[9];
  const float* Wo    = (const float*)d_in[10];
  const float* bo    = (const float*)d_in[11];
  const float* ln1g  = (const float*)d_in[12];
  const float* ln1b  = (const float*)d_in[13];
  const float* W1    = (const float*)d_in[14];
  const float* b1    = (const float*)d_in[15];
  const float* W2    = (const float*)d_in[16];
  const float* b2    = (const float*)d_in[17];
  const float* ln2g  = (const float*)d_in[18];
  const float* ln2b  = (const float*)d_in[19];
  const float* Wc    = (const float*)d_in[20];
  const float* bc    = (const float*)d_in[21];
  float* outp = (float*)d_out;

  char* p = (char*)d_ws;
  auto alloc = [&](size_t bytes) { char* r = p; p += (bytes + 255) & ~(size_t)255; return r; };
  float*  x     = (float*) alloc((size_t)TOK * Ee * 4);
  __bf16* xb    = (__bf16*)alloc((size_t)TOK * Ee * 2);
  float*  tmp   = (float*) alloc((size_t)TOK * Ee * 4);
  __bf16* attn  = (__bf16*)alloc((size_t)TOK * Ee * 2);
  char*   r1    = alloc((size_t)TOK * Ff * 2);          // union: [qkv|vt] / h1
  __bf16* qkv   = (__bf16*)r1;
  __bf16* vt    = (__bf16*)(r1 + (size_t)TOK * NQKV * 2);
  __bf16* h1    = (__bf16*)r1;
  __bf16* wqkvt = (__bf16*)alloc((size_t)Ll * NQKV * Ee * 2);
  __bf16* wot   = (__bf16*)alloc((size_t)Ll * Ee * Ee * 2);
  __bf16* w1t   = (__bf16*)alloc((size_t)Ll * Ff * Ee * 2);
  __bf16* w2t   = (__bf16*)alloc((size_t)Ll * Ee * Ff * 2);
  float*  part  = (float*) alloc((size_t)Bb * 16 * Ee * 4);

  // embedding
  embed_kernel<<<TOK, 256, 0, stream>>>(ids, emb, pe, x, xb);

  // weight prep (all layers at once)
  transpose_w_kernel<<<dim3(Ee/32, Ee/32, Ll), 256, 0, stream>>>(
      Wq, wqkvt,                         Ee, Ee, (size_t)Ee*Ee, (size_t)NQKV*Ee);
  transpose_w_kernel<<<dim3(Ee/32, Ee/32, Ll), 256, 0, stream>>>(
      Wk, wqkvt + (size_t)Ee*Ee,         Ee, Ee, (size_t)Ee*Ee, (size_t)NQKV*Ee);
  transpose_w_kernel<<<dim3(Ee/32, Ee/32, Ll), 256, 0, stream>>>(
      Wv, wqkvt + (size_t)2*Ee*Ee,       Ee, Ee, (size_t)Ee*Ee, (size_t)NQKV*Ee);
  transpose_w_kernel<<<dim3(Ee/32, Ee/32, Ll), 256, 0, stream>>>(
      Wo, wot,                           Ee, Ee, (size_t)Ee*Ee, (size_t)Ee*Ee);
  transpose_w_kernel<<<dim3(Ff/32, Ee/32, Ll), 256, 0, stream>>>(
      W1, w1t,                           Ee, Ff, (size_t)Ee*Ff, (size_t)Ff*Ee);
  transpose_w_kernel<<<dim3(Ee/32, Ff/32, Ll), 256, 0, stream>>>(
      W2, w2t,                           Ff, Ee, (size_t)Ff*Ee, (size_t)Ee*Ff);

  for (int l = 0; l < Ll; l++) {
    // QKV projection (packed N=2304), bf16 out (R6-verified config)
    gemm_kernel<true, false><<<64 * (NQKV/128), 256, 0, stream>>>(
        xb, wqkvt + (size_t)l*NQKV*Ee,
        bq + l*Ee, bk + l*Ee, bv + l*Ee, Ee,
        nullptr, qkv, TOK, NQKV, Ee);
    // V -> [b,h,d,s]
    vtrans_kernel<<<3072, 256, 0, stream>>>(qkv, vt);
    // flash attention: 8 waves/block, 128 q-rows per block
    attn_kernel<<<768, 512, 0, stream>>>(qkv, vt, amask, attn);
    // O projection, fp32 out: 8-wave blocks, grid 384 -> 12 waves/CU
    gemm8w_kernel<<<64 * (Ee/128), 512, 0, stream>>>(
        attn, wot + (size_t)l*Ee*Ee, bo + l*Ee, tmp, Ee, Ee);
    // x = LN(x + o)
    add_ln_kernel<<<TOK, 256, 0, stream>>>(x, tmp, ln1g + l*Ee, ln1b + l*Ee, x, xb);
    // FFN1 + relu, bf16 out (R6-verified config)
    gemm_kernel<true, true><<<64 * (Ff/128), 256, 0, stream>>>(
        xb, w1t + (size_t)l*Ff*Ee,
        b1 + l*Ff, b1 + l*Ff, b1 + l*Ff, Ff,
        nullptr, h1, TOK, Ff, Ee);
    // FFN2, fp32 out: 8-wave blocks, grid 384
    gemm8w_kernel<<<64 * (Ee/128), 512, 0, stream>>>(
        h1, w2t + (size_t)l*Ee*Ff, b2 + l*Ee, tmp, Ee, Ff);
    // x = LN(x + ffn)
    add_ln_kernel<<<TOK, 256, 0, stream>>>(x, tmp, ln2g + l*Ee, ln2b + l*Ee, x, xb);
  }

  // mean pool + classifier
  pool1_kernel<<<dim3(Bb, 16), 256, 0, stream>>>(x, part);
  pool2_kernel<<<Bb, 256, 0, stream>>>(part, Wc, bc, outp);
}